// Round 5
// baseline (897.858 us; speedup 1.0000x reference)
//
#include <hip/hip_runtime.h>
#include <hip/hip_bf16.h>
#include <stdint.h>

typedef unsigned short ushort_t;
using short8   = __attribute__((ext_vector_type(8))) short;
using float4v  = __attribute__((ext_vector_type(4))) float;
using int4v    = __attribute__((ext_vector_type(4))) int;

__device__ __forceinline__ float bf2f(ushort_t u) {
    union { unsigned int i; float f; } v;
    v.i = ((unsigned int)u) << 16;
    return v.f;
}
__device__ __forceinline__ ushort_t f2b(float f) {
    union { float f; unsigned int i; } v;
    v.f = f;
    unsigned int u = v.i;
    unsigned int r = (u + 0x7fffu + ((u >> 16) & 1u)) >> 16;   // RNE
    return (ushort_t)r;
}

// ---------------------------------------------------------------------------
// Convert W1 [128][64] fp32 and W2 [64][128] fp32 to bf16 (once per launch).
// ---------------------------------------------------------------------------
__global__ void convw_k(const float* __restrict__ W1, const float* __restrict__ W2,
                        ushort_t* __restrict__ w1b, ushort_t* __restrict__ w2b) {
    for (int i = threadIdx.x; i < 8192; i += 256) {
        w1b[i] = f2b(W1[i]);
        w2b[i] = f2b(W2[i]);
    }
}

// ---------------------------------------------------------------------------
// Transpose inp [64][N] fp32 -> X [N][64] bf16 (staged in d_out; consumed by
// binagg_k before mlp_k overwrites d_out — stream-ordered, lifetimes disjoint)
// ---------------------------------------------------------------------------
__global__ void transpose_k(const float* __restrict__ inp,
                            ushort_t* __restrict__ X, int N) {
    __shared__ float tile[64][65];
    int tx = threadIdx.x & 63;
    int ty = threadIdx.x >> 6;
    int n0 = blockIdx.x * 64;
#pragma unroll
    for (int r = 0; r < 16; ++r) {
        int d = ty * 16 + r;
        int n = n0 + tx;
        if (n < N) tile[d][tx] = inp[(size_t)d * N + n];
    }
    __syncthreads();
#pragma unroll
    for (int r = 0; r < 16; ++r) {
        int nl = ty * 16 + r;
        int n  = n0 + nl;
        if (n < N) X[(size_t)n * 64 + tx] = f2b(tile[tx][nl]);
    }
}

// ---------------------------------------------------------------------------
// LDS-binned aggregation: block b owns dst nodes [b*256, b*256+256) with a
// fp32 accumulator tile in LDS (64 KB). Every block scans the full edge list
// (int4 dst loads, coalesced), ballot-selects matching edges, and for each
// match all 64 lanes cooperatively accumulate the 128B X row into LDS
// (ds_add_f32, conflict-free). No global atomics, no CSR materialization.
// ---------------------------------------------------------------------------
#define RNODES 256
#define BINTHREADS 512

__global__ __launch_bounds__(BINTHREADS) void binagg_k(
        const ushort_t* __restrict__ X,
        const int* __restrict__ src,
        const int* __restrict__ dst,
        float* __restrict__ agg, int N, int E) {
    __shared__ float lagg[RNODES * 64];          // 64 KB
    int tid  = threadIdx.x;
    int lane = tid & 63;
    int lo   = blockIdx.x * RNODES;

    float4v z4 = {0.f, 0.f, 0.f, 0.f};
    for (int i = tid; i < RNODES * 16; i += BINTHREADS)
        ((float4v*)lagg)[i] = z4;
    __syncthreads();

    const int4v* dst4 = (const int4v*)dst;
    const int4v* src4 = (const int4v*)src;
    int nq = E >> 2;

    for (int i = tid; i < nq; i += BINTHREADS) {
        int4v d = dst4[i];
        unsigned l0 = (unsigned)(d[0] - lo);
        unsigned l1 = (unsigned)(d[1] - lo);
        unsigned l2 = (unsigned)(d[2] - lo);
        unsigned l3 = (unsigned)(d[3] - lo);
        bool m0 = l0 < (unsigned)RNODES, m1 = l1 < (unsigned)RNODES;
        bool m2 = l2 < (unsigned)RNODES, m3 = l3 < (unsigned)RNODES;
        int4v s = {0, 0, 0, 0};
        if (m0 | m1 | m2 | m3) s = src4[i];

#define PROC(mj, lj, sj)                                                \
        {                                                               \
            unsigned long long mask = __ballot(mj);                     \
            while (mask) {                                              \
                int l = __ffsll(mask) - 1;                              \
                mask &= mask - 1;                                       \
                int dls = __shfl((int)(lj), l);                         \
                int ss  = __shfl((int)(sj), l);                         \
                float v = bf2f(X[(size_t)ss * 64 + lane]);              \
                atomicAdd(&lagg[dls * 64 + lane], v);                   \
            }                                                           \
        }
        PROC(m0, l0, s[0]);
        PROC(m1, l1, s[1]);
        PROC(m2, l2, s[2]);
        PROC(m3, l3, s[3]);
#undef PROC
    }

    // tail (E % 4) — wave 0 only
    if (tid < 64) {
        int e  = (nq << 2) + lane;
        int dd = (e < E) ? dst[e] : -1;
        unsigned dl = (unsigned)(dd - lo);
        bool m = dl < (unsigned)RNODES;
        int sv = m ? src[e] : 0;
        unsigned long long mask = __ballot(m);
        while (mask) {
            int l = __ffsll(mask) - 1;
            mask &= mask - 1;
            int dls = __shfl((int)dl, l);
            int ss  = __shfl(sv, l);
            float v = bf2f(X[(size_t)ss * 64 + lane]);
            atomicAdd(&lagg[dls * 64 + lane], v);
        }
    }
    __syncthreads();

    // dense coalesced writeback of owned agg rows
    int hi = N - lo;
    if (hi > RNODES) hi = RNODES;
    if (hi <= 0) return;
    int n4v = hi * 16;
    float4v* op = (float4v*)(agg + (size_t)lo * 64);
    const float4v* lp = (const float4v*)lagg;
    for (int i = tid; i < n4v; i += BINTHREADS) op[i] = lp[i];
}

// ---------------------------------------------------------------------------
// Fused 2-layer MLP via bf16 MFMA 16x16x32 (fp32 acc).
// Frag maps (verified, guide §3):
//   A[m=lane&15][k=(lane>>4)*8+j], B[k=(lane>>4)*8+j][n=lane&15],
//   D[m=(lane>>4)*4+r][n=lane&15]
// ---------------------------------------------------------------------------
#define HPITCH 136

__global__ __launch_bounds__(256) void mlp_k(
        const float* __restrict__ agg,
        const ushort_t* __restrict__ W1, const float* __restrict__ b1,
        const ushort_t* __restrict__ W2, const float* __restrict__ b2,
        float* __restrict__ out, int N) {
    __shared__ ushort_t h_s[4][16 * HPITCH];

    int wave = threadIdx.x >> 6;
    int lane = threadIdx.x & 63;
    int row  = lane & 15;
    int quad = lane >> 4;
    int n0   = blockIdx.x * 64 + wave * 16;

    int anode = n0 + row;
    if (anode > N - 1) anode = N - 1;
    const float* ap = agg + (size_t)anode * 64 + quad * 8;

    short8 a0, a1;
    {
        float4v f0 = *(const float4v*)(ap);
        float4v f1 = *(const float4v*)(ap + 4);
        float4v f2 = *(const float4v*)(ap + 32);
        float4v f3 = *(const float4v*)(ap + 36);
#pragma unroll
        for (int j = 0; j < 4; ++j) {
            a0[j]     = (short)f2b(f0[j]);
            a0[j + 4] = (short)f2b(f1[j]);
            a1[j]     = (short)f2b(f2[j]);
            a1[j + 4] = (short)f2b(f3[j]);
        }
    }

    float4v zero = {0.f, 0.f, 0.f, 0.f};
    float4v acc[8];
#pragma unroll
    for (int nt = 0; nt < 8; ++nt) acc[nt] = zero;

#pragma unroll
    for (int nt = 0; nt < 8; ++nt) {
        const ushort_t* wp = W1 + (size_t)(nt * 16 + row) * 64 + quad * 8;
        short8 bf0 = *(const short8*)(wp);
        short8 bf1 = *(const short8*)(wp + 32);
        acc[nt] = __builtin_amdgcn_mfma_f32_16x16x32_bf16(a0, bf0, acc[nt], 0, 0, 0);
        acc[nt] = __builtin_amdgcn_mfma_f32_16x16x32_bf16(a1, bf1, acc[nt], 0, 0, 0);
    }

    ushort_t* hw = h_s[wave];
#pragma unroll
    for (int nt = 0; nt < 8; ++nt) {
        float bias = b1[nt * 16 + row];
#pragma unroll
        for (int r = 0; r < 4; ++r) {
            float v = acc[nt][r] + bias;
            v = v > 0.f ? v : 0.f;
            hw[(quad * 4 + r) * HPITCH + nt * 16 + row] = f2b(v);
        }
    }
    __syncthreads();

    short8 a2[4];
#pragma unroll
    for (int kt = 0; kt < 4; ++kt)
        a2[kt] = *(const short8*)(hw + row * HPITCH + kt * 32 + quad * 8);

    float4v acc2[4];
#pragma unroll
    for (int nt = 0; nt < 4; ++nt) acc2[nt] = zero;

#pragma unroll
    for (int nt = 0; nt < 4; ++nt) {
#pragma unroll
        for (int kt = 0; kt < 4; ++kt) {
            short8 bfr = *(const short8*)(W2 + (size_t)(nt * 16 + row) * 128 +
                                          kt * 32 + quad * 8);
            acc2[nt] = __builtin_amdgcn_mfma_f32_16x16x32_bf16(a2[kt], bfr, acc2[nt], 0, 0, 0);
        }
    }

    int node = n0 + quad * 4;
    if (node < N) {
#pragma unroll
        for (int nt = 0; nt < 4; ++nt) {
            int ko = nt * 16 + row;
            float bias = b2[ko];
            float4v pk;
#pragma unroll
            for (int r = 0; r < 4; ++r) pk[r] = acc2[nt][r] + bias;
            *(float4v*)(out + (size_t)ko * N + node) = pk;
        }
    }
}

// ---------------------------------------------------------------------------
extern "C" void kernel_launch(void* const* d_in, const int* in_sizes, int n_in,
                              void* d_out, int out_size, void* d_ws, size_t ws_size,
                              hipStream_t stream) {
    const float* inp = (const float*)d_in[0];   // [64][N] fp32
    const int*   src = (const int*)d_in[1];
    const int*   dst = (const int*)d_in[2];
    const float* W1  = (const float*)d_in[3];   // [128][64] fp32
    const float* b1  = (const float*)d_in[4];   // [128] fp32
    const float* W2  = (const float*)d_in[5];   // [64][128] fp32
    const float* b2  = (const float*)d_in[6];   // [64] fp32
    float* out = (float*)d_out;                 // [64][N] fp32

    int N = in_sizes[0] / 64;
    int E = in_sizes[1];

    // ws: agg fp32[N*64] (25.6 MB) + w1b/w2b bf16 (32 KB)
    float*    agg = (float*)d_ws;
    ushort_t* w1b = (ushort_t*)((char*)d_ws + (size_t)N * 64 * sizeof(float));
    ushort_t* w2b = w1b + 8192;

    // X bf16[N*64] staged in d_out's first half; dead before mlp_k writes out.
    ushort_t* X = (ushort_t*)d_out;

    convw_k<<<1, 256, 0, stream>>>(W1, W2, w1b, w2b);

    int tb = (N + 63) / 64;
    transpose_k<<<tb, 256, 0, stream>>>(inp, X, N);

    int gb = (N + RNODES - 1) / RNODES;
    binagg_k<<<gb, BINTHREADS, 0, stream>>>(X, src, dst, agg, N, E);

    mlp_k<<<tb, 256, 0, stream>>>(agg, w1b, b1, w2b, b2, out, N);
}

// Round 6
// 884.132 us; speedup vs baseline: 1.0155x; 1.0155x over previous
//
#include <hip/hip_runtime.h>
#include <hip/hip_bf16.h>
#include <stdint.h>

typedef unsigned short ushort_t;
using short8   = __attribute__((ext_vector_type(8))) short;
using float4v  = __attribute__((ext_vector_type(4))) float;

#define BSH    8          // bucket = 256 consecutive dst nodes
#define BUCKW  256
#define CAP    6144       // per-bucket bin capacity (avg load 4096, +32 sigma)
#define NBMAX  512

__device__ __forceinline__ float bf2f(ushort_t u) {
    union { unsigned int i; float f; } v;
    v.i = ((unsigned int)u) << 16;
    return v.f;
}
__device__ __forceinline__ ushort_t f2b(float f) {
    union { float f; unsigned int i; } v;
    v.f = f;
    unsigned int u = v.i;
    unsigned int r = (u + 0x7fffu + ((u >> 16) & 1u)) >> 16;   // RNE
    return (ushort_t)r;
}

// ---------------------------------------------------------------------------
// Convert weights fp32->bf16 + init per-bucket global cursors gcur[b]=b*CAP.
// ---------------------------------------------------------------------------
__global__ void convw_k(const float* __restrict__ W1, const float* __restrict__ W2,
                        ushort_t* __restrict__ w1b, ushort_t* __restrict__ w2b,
                        int* __restrict__ gcur, int NB) {
    for (int i = threadIdx.x; i < 8192; i += 256) {
        w1b[i] = f2b(W1[i]);
        w2b[i] = f2b(W2[i]);
    }
    for (int b = threadIdx.x; b < NB; b += 256) gcur[b] = b * CAP;
}

// ---------------------------------------------------------------------------
// Transpose inp [64][N] fp32 -> X [N][64] bf16 (staged in d_out; consumed by
// bagg_k before mlp_k overwrites d_out — stream-ordered, lifetimes disjoint).
// ---------------------------------------------------------------------------
__global__ void transpose_k(const float* __restrict__ inp,
                            ushort_t* __restrict__ X, int N) {
    __shared__ float tile[64][65];
    int tx = threadIdx.x & 63;
    int ty = threadIdx.x >> 6;
    int n0 = blockIdx.x * 64;
#pragma unroll
    for (int r = 0; r < 16; ++r) {
        int d = ty * 16 + r;
        int n = n0 + tx;
        if (n < N) tile[d][tx] = inp[(size_t)d * N + n];
    }
    __syncthreads();
#pragma unroll
    for (int r = 0; r < 16; ++r) {
        int nl = ty * 16 + r;
        int n  = n0 + nl;
        if (n < N) X[(size_t)n * 64 + tx] = f2b(tile[tx][nl]);
    }
}

// ---------------------------------------------------------------------------
// Two-sweep binning. Block processes a contiguous edge chunk:
//  sweep 1: count chunk edges per bucket (LDS).
//  claim:   one global atomicAdd per (block,bucket) -> block-PRIVATE span.
//  sweep 2: write pack=(dst_local<<24|src) into own span.
// Same-line writers are the same block => L2 write-back coalesces lines
// (vs R4 scatter_k: random 4B writes from all XCDs => 105 MB write-through).
// ---------------------------------------------------------------------------
__global__ __launch_bounds__(256) void bin_k(
        const int* __restrict__ src, const int* __restrict__ dst,
        int* __restrict__ gcur, unsigned* __restrict__ bin, int E, int NB) {
    __shared__ int lcnt[NBMAX];
    __shared__ int gbase[NBMAX];
    __shared__ int lcur[NBMAX];
    int tid   = threadIdx.x;
    int chunk = (E + gridDim.x - 1) / gridDim.x;
    int s0 = blockIdx.x * chunk;
    int s1 = s0 + chunk;
    if (s1 > E) s1 = E;

    for (int b = tid; b < NB; b += 256) lcnt[b] = 0;
    __syncthreads();

    for (int e = s0 + tid; e < s1; e += 256)
        atomicAdd(&lcnt[dst[e] >> BSH], 1);
    __syncthreads();

    for (int b = tid; b < NB; b += 256) {
        int c = lcnt[b];
        gbase[b] = c ? atomicAdd(&gcur[b], c) : 0;
        lcur[b]  = 0;
    }
    __syncthreads();

    for (int e = s0 + tid; e < s1; e += 256) {
        int d = dst[e];
        int b = d >> BSH;
        int pos = gbase[b] + atomicAdd(&lcur[b], 1);
        if (pos < (b + 1) * CAP)   // overflow guard (statistically unreachable)
            bin[pos] = ((unsigned)(d & (BUCKW - 1)) << 24) | (unsigned)src[e];
    }
}

// ---------------------------------------------------------------------------
// Per-bucket aggregation: block b owns dst nodes [b*256, b*256+256), fp32
// accumulators in LDS (64 KB). Reads ONLY its bucket's packed edges (no scan
// redundancy), gathers 128B X rows, ds_add conflict-free (2-way aliasing).
// Writes agg rows densely once. No global atomics.
// ---------------------------------------------------------------------------
__global__ __launch_bounds__(512) void bagg_k(
        const ushort_t* __restrict__ X, const unsigned* __restrict__ bin,
        const int* __restrict__ gcur, float* __restrict__ agg, int N) {
    __shared__ float acc[BUCKW * 64];            // 64 KB
    int tid  = threadIdx.x;
    int lane = tid & 63;
    int wave = tid >> 6;                         // 0..7
    int b    = blockIdx.x;
    int lo   = b << BSH;

    float4v z = {0.f, 0.f, 0.f, 0.f};
    for (int i = tid; i < BUCKW * 16; i += 512) ((float4v*)acc)[i] = z;
    __syncthreads();

    int cnt = gcur[b] - b * CAP;
    if (cnt > CAP) cnt = CAP;
    const unsigned* bb = bin + (size_t)b * CAP;

    for (int base = wave * 64; base < cnt; base += 512) {
        int m = cnt - base;
        if (m > 64) m = 64;
        unsigned pk = 0;
        if (lane < m) pk = bb[base + lane];
        for (int j = 0; j < m; ++j) {
            unsigned p  = (unsigned)__shfl((int)pk, j);
            int srcn    = (int)(p & 0xFFFFFFu);
            int nl      = (int)(p >> 24);
            float v = bf2f(X[(size_t)srcn * 64 + lane]);
            atomicAdd(&acc[nl * 64 + lane], v);
        }
    }
    __syncthreads();

    int rows = N - lo;
    if (rows > BUCKW) rows = BUCKW;
    if (rows <= 0) return;
    float4v* op = (float4v*)(agg + (size_t)lo * 64);
    const float4v* lp = (const float4v*)acc;
    for (int i = tid; i < rows * 16; i += 512) op[i] = lp[i];
}

// ---------------------------------------------------------------------------
// Fused 2-layer MLP via bf16 MFMA 16x16x32 (fp32 acc).
// Frag maps (verified, guide §3):
//   A[m=lane&15][k=(lane>>4)*8+j], B[k=(lane>>4)*8+j][n=lane&15],
//   D[m=(lane>>4)*4+r][n=lane&15]
// ---------------------------------------------------------------------------
#define HPITCH 136

__global__ __launch_bounds__(256) void mlp_k(
        const float* __restrict__ agg,
        const ushort_t* __restrict__ W1, const float* __restrict__ b1,
        const ushort_t* __restrict__ W2, const float* __restrict__ b2,
        float* __restrict__ out, int N) {
    __shared__ ushort_t h_s[4][16 * HPITCH];

    int wave = threadIdx.x >> 6;
    int lane = threadIdx.x & 63;
    int row  = lane & 15;
    int quad = lane >> 4;
    int n0   = blockIdx.x * 64 + wave * 16;

    int anode = n0 + row;
    if (anode > N - 1) anode = N - 1;
    const float* ap = agg + (size_t)anode * 64 + quad * 8;

    short8 a0, a1;
    {
        float4v f0 = *(const float4v*)(ap);
        float4v f1 = *(const float4v*)(ap + 4);
        float4v f2 = *(const float4v*)(ap + 32);
        float4v f3 = *(const float4v*)(ap + 36);
#pragma unroll
        for (int j = 0; j < 4; ++j) {
            a0[j]     = (short)f2b(f0[j]);
            a0[j + 4] = (short)f2b(f1[j]);
            a1[j]     = (short)f2b(f2[j]);
            a1[j + 4] = (short)f2b(f3[j]);
        }
    }

    float4v zero = {0.f, 0.f, 0.f, 0.f};
    float4v acc[8];
#pragma unroll
    for (int nt = 0; nt < 8; ++nt) acc[nt] = zero;

#pragma unroll
    for (int nt = 0; nt < 8; ++nt) {
        const ushort_t* wp = W1 + (size_t)(nt * 16 + row) * 64 + quad * 8;
        short8 bf0 = *(const short8*)(wp);
        short8 bf1 = *(const short8*)(wp + 32);
        acc[nt] = __builtin_amdgcn_mfma_f32_16x16x32_bf16(a0, bf0, acc[nt], 0, 0, 0);
        acc[nt] = __builtin_amdgcn_mfma_f32_16x16x32_bf16(a1, bf1, acc[nt], 0, 0, 0);
    }

    ushort_t* hw = h_s[wave];
#pragma unroll
    for (int nt = 0; nt < 8; ++nt) {
        float bias = b1[nt * 16 + row];
#pragma unroll
        for (int r = 0; r < 4; ++r) {
            float v = acc[nt][r] + bias;
            v = v > 0.f ? v : 0.f;
            hw[(quad * 4 + r) * HPITCH + nt * 16 + row] = f2b(v);
        }
    }
    __syncthreads();

    short8 a2[4];
#pragma unroll
    for (int kt = 0; kt < 4; ++kt)
        a2[kt] = *(const short8*)(hw + row * HPITCH + kt * 32 + quad * 8);

    float4v acc2[4];
#pragma unroll
    for (int nt = 0; nt < 4; ++nt) acc2[nt] = zero;

#pragma unroll
    for (int nt = 0; nt < 4; ++nt) {
#pragma unroll
        for (int kt = 0; kt < 4; ++kt) {
            short8 bfr = *(const short8*)(W2 + (size_t)(nt * 16 + row) * 128 +
                                          kt * 32 + quad * 8);
            acc2[nt] = __builtin_amdgcn_mfma_f32_16x16x32_bf16(a2[kt], bfr, acc2[nt], 0, 0, 0);
        }
    }

    int node = n0 + quad * 4;
    if (node < N) {
#pragma unroll
        for (int nt = 0; nt < 4; ++nt) {
            int ko = nt * 16 + row;
            float bias = b2[ko];
            float4v pk;
#pragma unroll
            for (int r = 0; r < 4; ++r) pk[r] = acc2[nt][r] + bias;
            *(float4v*)(out + (size_t)ko * N + node) = pk;
        }
    }
}

// ---------------------------------------------------------------------------
extern "C" void kernel_launch(void* const* d_in, const int* in_sizes, int n_in,
                              void* d_out, int out_size, void* d_ws, size_t ws_size,
                              hipStream_t stream) {
    const float* inp = (const float*)d_in[0];   // [64][N] fp32
    const int*   src = (const int*)d_in[1];
    const int*   dst = (const int*)d_in[2];
    const float* W1  = (const float*)d_in[3];   // [128][64] fp32
    const float* b1  = (const float*)d_in[4];   // [128] fp32
    const float* W2  = (const float*)d_in[5];   // [64][128] fp32
    const float* b2  = (const float*)d_in[6];   // [64] fp32
    float* out = (float*)d_out;                 // [64][N] fp32

    int N = in_sizes[0] / 64;
    int E = in_sizes[1];
    int NB = (N + BUCKW - 1) >> BSH;            // 391 for N=100000 (<= NBMAX)

    // ws: agg fp32[N*64] (25.6 MB) + w1b/w2b bf16 (32 KB) + gcur int[NBMAX]
    float*    agg  = (float*)d_ws;
    ushort_t* w1b  = (ushort_t*)((char*)d_ws + (size_t)N * 64 * sizeof(float));
    ushort_t* w2b  = w1b + 8192;
    int*      gcur = (int*)(w2b + 8192);

    // d_out staging (dead before mlp_k overwrites d_out):
    //   X bf16[N*64] (12.8 MB) | bin u32[NB*CAP] (9.6 MB)  — total 22.4 MB
    char*     ob  = (char*)d_out;
    ushort_t* X   = (ushort_t*)ob;
    unsigned* bin = (unsigned*)(ob + (size_t)N * 64 * 2);

    convw_k<<<1, 256, 0, stream>>>(W1, W2, w1b, w2b, gcur, NB);

    int tb = (N + 63) / 64;
    transpose_k<<<tb, 256, 0, stream>>>(inp, X, N);

    bin_k<<<256, 256, 0, stream>>>(src, dst, gcur, bin, E, NB);
    bagg_k<<<NB, 512, 0, stream>>>(X, bin, gcur, agg, N);

    mlp_k<<<tb, 256, 0, stream>>>(agg, w1b, b1, w2b, b2, out, N);
}

// Round 7
// 844.677 us; speedup vs baseline: 1.0630x; 1.0467x over previous
//
#include <hip/hip_runtime.h>
#include <hip/hip_bf16.h>
#include <stdint.h>

typedef unsigned short ushort_t;
using short8   = __attribute__((ext_vector_type(8))) short;
using ushort8  = __attribute__((ext_vector_type(8))) unsigned short;
using float4v  = __attribute__((ext_vector_type(4))) float;

#define BSH    7          // bucket = 128 consecutive dst nodes
#define BUCKW  128
#define CAP    3072       // per-bucket capacity (avg 2048, +22 sigma)
#define NBMAX  1024
#define APITCH 65         // odd pitch => LDS banks (nl+dim)%32, uniform

__device__ __forceinline__ float bf2f(ushort_t u) {
    union { unsigned int i; float f; } v;
    v.i = ((unsigned int)u) << 16;
    return v.f;
}
__device__ __forceinline__ ushort_t f2b(float f) {
    union { float f; unsigned int i; } v;
    v.f = f;
    unsigned int u = v.i;
    unsigned int r = (u + 0x7fffu + ((u >> 16) & 1u)) >> 16;   // RNE
    return (ushort_t)r;
}

// ---------------------------------------------------------------------------
// Convert weights fp32->bf16 + init per-bucket global cursors gcur[b]=b*CAP.
// ---------------------------------------------------------------------------
__global__ void convw_k(const float* __restrict__ W1, const float* __restrict__ W2,
                        ushort_t* __restrict__ w1b, ushort_t* __restrict__ w2b,
                        int* __restrict__ gcur, int NB) {
    for (int i = threadIdx.x; i < 8192; i += 256) {
        w1b[i] = f2b(W1[i]);
        w2b[i] = f2b(W2[i]);
    }
    for (int b = threadIdx.x; b < NB; b += 256) gcur[b] = b * CAP;
}

// ---------------------------------------------------------------------------
// Transpose inp [64][N] fp32 -> X [N][64] bf16 (staged in d_out; consumed by
// bagg_k before mlp_k overwrites d_out — stream-ordered, lifetimes disjoint).
// ---------------------------------------------------------------------------
__global__ void transpose_k(const float* __restrict__ inp,
                            ushort_t* __restrict__ X, int N) {
    __shared__ float tile[64][65];
    int tx = threadIdx.x & 63;
    int ty = threadIdx.x >> 6;
    int n0 = blockIdx.x * 64;
#pragma unroll
    for (int r = 0; r < 16; ++r) {
        int d = ty * 16 + r;
        int n = n0 + tx;
        if (n < N) tile[d][tx] = inp[(size_t)d * N + n];
    }
    __syncthreads();
#pragma unroll
    for (int r = 0; r < 16; ++r) {
        int nl = ty * 16 + r;
        int n  = n0 + nl;
        if (n < N) X[(size_t)n * 64 + tx] = f2b(tile[tx][nl]);
    }
}

// ---------------------------------------------------------------------------
// Two-sweep binning (same-block line ownership => coalesced write-back):
//  sweep 1: count chunk edges per bucket (LDS), claim block-private spans,
//  sweep 2: write pack=(dst_local<<24|src) into own span.
// 128 blocks x 512 threads: span avg = 12500/782 ~ 16 entries = 1 line.
// ---------------------------------------------------------------------------
__global__ __launch_bounds__(512) void bin_k(
        const int* __restrict__ src, const int* __restrict__ dst,
        int* __restrict__ gcur, unsigned* __restrict__ bin, int E, int NB) {
    __shared__ int lcnt[NBMAX];
    __shared__ int gbase[NBMAX];
    __shared__ int lcur[NBMAX];
    int tid   = threadIdx.x;
    int chunk = (E + gridDim.x - 1) / gridDim.x;
    int s0 = blockIdx.x * chunk;
    int s1 = s0 + chunk;
    if (s1 > E) s1 = E;

    for (int b = tid; b < NB; b += 512) lcnt[b] = 0;
    __syncthreads();

    for (int e = s0 + tid; e < s1; e += 512)
        atomicAdd(&lcnt[dst[e] >> BSH], 1);
    __syncthreads();

    for (int b = tid; b < NB; b += 512) {
        int c = lcnt[b];
        gbase[b] = c ? atomicAdd(&gcur[b], c) : 0;
        lcur[b]  = 0;
    }
    __syncthreads();

    for (int e = s0 + tid; e < s1; e += 512) {
        int d = dst[e];
        int b = d >> BSH;
        int pos = gbase[b] + atomicAdd(&lcur[b], 1);
        if (pos < (b + 1) * CAP)   // overflow guard (statistically unreachable)
            bin[pos] = ((unsigned)(d & (BUCKW - 1)) << 24) | (unsigned)src[e];
    }
}

// ---------------------------------------------------------------------------
// Per-bucket aggregation, ONE EDGE PER LANE (fully parallel, no serial
// chains): lane loads its packed edge, reads its X row as 8x16B dwordx4
// (64 independent row-loads in flight per wave), then 64 wave-wide
// ds_add_f32 (lanes target different nodes; pitch 65 => uniform banks).
// 33 KB LDS => 4 blocks/CU; 782 blocks cover all 256 CUs.
// ---------------------------------------------------------------------------
__global__ __launch_bounds__(512) void bagg_k(
        const ushort_t* __restrict__ X, const unsigned* __restrict__ bin,
        const int* __restrict__ gcur, float* __restrict__ agg, int N) {
    __shared__ float acc[BUCKW * APITCH];        // 33280 B
    int tid = threadIdx.x;
    int b   = blockIdx.x;
    int lo  = b << BSH;

    for (int i = tid; i < BUCKW * APITCH; i += 512) acc[i] = 0.f;
    __syncthreads();

    int cnt = gcur[b] - b * CAP;
    if (cnt > CAP) cnt = CAP;
    const unsigned* bb = bin + (size_t)b * CAP;

    for (int base = 0; base < cnt; base += 512) {
        int i = base + tid;
        if (i < cnt) {
            unsigned p = bb[i];
            int srcn = (int)(p & 0xFFFFFFu);
            int nl   = (int)(p >> 24);
            const ushort8* xp = (const ushort8*)(X + (size_t)srcn * 64);
            float* ap = acc + nl * APITCH;
#pragma unroll
            for (int r = 0; r < 8; ++r) {
                ushort8 u = xp[r];                  // 16B load, lane-private row
#pragma unroll
                for (int j = 0; j < 8; ++j)
                    atomicAdd(ap + r * 8 + j, bf2f(u[j]));
            }
        }
    }
    __syncthreads();

    int rows = N - lo;
    if (rows > BUCKW) rows = BUCKW;
    if (rows <= 0) return;
    // coalesced 4B stores; LDS reads scalar (pitch 65), cheap
    for (int i = tid; i < rows * 64; i += 512) {
        int n = i >> 6, d = i & 63;
        agg[(size_t)(lo + n) * 64 + d] = acc[n * APITCH + d];
    }
}

// ---------------------------------------------------------------------------
// Fused 2-layer MLP via bf16 MFMA 16x16x32 (fp32 acc).
// Frag maps (verified, guide §3):
//   A[m=lane&15][k=(lane>>4)*8+j], B[k=(lane>>4)*8+j][n=lane&15],
//   D[m=(lane>>4)*4+r][n=lane&15]
// ---------------------------------------------------------------------------
#define HPITCH 136

__global__ __launch_bounds__(256) void mlp_k(
        const float* __restrict__ agg,
        const ushort_t* __restrict__ W1, const float* __restrict__ b1,
        const ushort_t* __restrict__ W2, const float* __restrict__ b2,
        float* __restrict__ out, int N) {
    __shared__ ushort_t h_s[4][16 * HPITCH];

    int wave = threadIdx.x >> 6;
    int lane = threadIdx.x & 63;
    int row  = lane & 15;
    int quad = lane >> 4;
    int n0   = blockIdx.x * 64 + wave * 16;

    int anode = n0 + row;
    if (anode > N - 1) anode = N - 1;
    const float* ap = agg + (size_t)anode * 64 + quad * 8;

    short8 a0, a1;
    {
        float4v f0 = *(const float4v*)(ap);
        float4v f1 = *(const float4v*)(ap + 4);
        float4v f2 = *(const float4v*)(ap + 32);
        float4v f3 = *(const float4v*)(ap + 36);
#pragma unroll
        for (int j = 0; j < 4; ++j) {
            a0[j]     = (short)f2b(f0[j]);
            a0[j + 4] = (short)f2b(f1[j]);
            a1[j]     = (short)f2b(f2[j]);
            a1[j + 4] = (short)f2b(f3[j]);
        }
    }

    float4v zero = {0.f, 0.f, 0.f, 0.f};
    float4v acc[8];
#pragma unroll
    for (int nt = 0; nt < 8; ++nt) acc[nt] = zero;

#pragma unroll
    for (int nt = 0; nt < 8; ++nt) {
        const ushort_t* wp = W1 + (size_t)(nt * 16 + row) * 64 + quad * 8;
        short8 bf0 = *(const short8*)(wp);
        short8 bf1 = *(const short8*)(wp + 32);
        acc[nt] = __builtin_amdgcn_mfma_f32_16x16x32_bf16(a0, bf0, acc[nt], 0, 0, 0);
        acc[nt] = __builtin_amdgcn_mfma_f32_16x16x32_bf16(a1, bf1, acc[nt], 0, 0, 0);
    }

    ushort_t* hw = h_s[wave];
#pragma unroll
    for (int nt = 0; nt < 8; ++nt) {
        float bias = b1[nt * 16 + row];
#pragma unroll
        for (int r = 0; r < 4; ++r) {
            float v = acc[nt][r] + bias;
            v = v > 0.f ? v : 0.f;
            hw[(quad * 4 + r) * HPITCH + nt * 16 + row] = f2b(v);
        }
    }
    __syncthreads();

    short8 a2[4];
#pragma unroll
    for (int kt = 0; kt < 4; ++kt)
        a2[kt] = *(const short8*)(hw + row * HPITCH + kt * 32 + quad * 8);

    float4v acc2[4];
#pragma unroll
    for (int nt = 0; nt < 4; ++nt) acc2[nt] = zero;

#pragma unroll
    for (int nt = 0; nt < 4; ++nt) {
#pragma unroll
        for (int kt = 0; kt < 4; ++kt) {
            short8 bfr = *(const short8*)(W2 + (size_t)(nt * 16 + row) * 128 +
                                          kt * 32 + quad * 8);
            acc2[nt] = __builtin_amdgcn_mfma_f32_16x16x32_bf16(a2[kt], bfr, acc2[nt], 0, 0, 0);
        }
    }

    int node = n0 + quad * 4;
    if (node < N) {
#pragma unroll
        for (int nt = 0; nt < 4; ++nt) {
            int ko = nt * 16 + row;
            float bias = b2[ko];
            float4v pk;
#pragma unroll
            for (int r = 0; r < 4; ++r) pk[r] = acc2[nt][r] + bias;
            *(float4v*)(out + (size_t)ko * N + node) = pk;
        }
    }
}

// ---------------------------------------------------------------------------
extern "C" void kernel_launch(void* const* d_in, const int* in_sizes, int n_in,
                              void* d_out, int out_size, void* d_ws, size_t ws_size,
                              hipStream_t stream) {
    const float* inp = (const float*)d_in[0];   // [64][N] fp32
    const int*   src = (const int*)d_in[1];
    const int*   dst = (const int*)d_in[2];
    const float* W1  = (const float*)d_in[3];   // [128][64] fp32
    const float* b1  = (const float*)d_in[4];   // [128] fp32
    const float* W2  = (const float*)d_in[5];   // [64][128] fp32
    const float* b2  = (const float*)d_in[6];   // [64] fp32
    float* out = (float*)d_out;                 // [64][N] fp32

    int N = in_sizes[0] / 64;
    int E = in_sizes[1];
    int NB = (N + BUCKW - 1) >> BSH;            // 782 for N=100000 (<= NBMAX)

    // ws: agg fp32[N*64] (25.6 MB) + w1b/w2b bf16 (32 KB) + gcur int[NBMAX]
    float*    agg  = (float*)d_ws;
    ushort_t* w1b  = (ushort_t*)((char*)d_ws + (size_t)N * 64 * sizeof(float));
    ushort_t* w2b  = w1b + 8192;
    int*      gcur = (int*)(w2b + 8192);

    // d_out staging (dead before mlp_k overwrites d_out):
    //   X bf16[N*64] (12.8 MB) | bin u32[NB*CAP] (9.6 MB)  — total 22.4 MB
    char*     ob  = (char*)d_out;
    ushort_t* X   = (ushort_t*)ob;
    unsigned* bin = (unsigned*)(ob + (size_t)N * 64 * 2);

    convw_k<<<1, 256, 0, stream>>>(W1, W2, w1b, w2b, gcur, NB);

    int tb = (N + 63) / 64;
    transpose_k<<<tb, 256, 0, stream>>>(inp, X, N);

    bin_k<<<128, 512, 0, stream>>>(src, dst, gcur, bin, E, NB);
    bagg_k<<<NB, 512, 0, stream>>>(X, bin, gcur, agg, N);

    mlp_k<<<tb, 256, 0, stream>>>(agg, w1b, b1, w2b, b2, out, N);
}

// Round 8
// 213.799 us; speedup vs baseline: 4.1995x; 3.9508x over previous
//
#include <hip/hip_runtime.h>
#include <hip/hip_bf16.h>
#include <stdint.h>

typedef unsigned short ushort_t;
using short8   = __attribute__((ext_vector_type(8))) short;
using float4v  = __attribute__((ext_vector_type(4))) float;

#define BSH    7          // bucket = 128 consecutive dst nodes
#define BUCKW  128
#define CAP    3072       // per-bucket capacity (avg 2046, +22 sigma)
#define NBMAX  1024

__device__ __forceinline__ float bf2f(ushort_t u) {
    union { unsigned int i; float f; } v;
    v.i = ((unsigned int)u) << 16;
    return v.f;
}
__device__ __forceinline__ ushort_t f2b(float f) {
    union { float f; unsigned int i; } v;
    v.f = f;
    unsigned int u = v.i;
    unsigned int r = (u + 0x7fffu + ((u >> 16) & 1u)) >> 16;   // RNE
    return (ushort_t)r;
}

// ---------------------------------------------------------------------------
// Convert weights fp32->bf16 + init per-bucket global cursors gcur[b]=b*CAP.
// ---------------------------------------------------------------------------
__global__ void convw_k(const float* __restrict__ W1, const float* __restrict__ W2,
                        ushort_t* __restrict__ w1b, ushort_t* __restrict__ w2b,
                        int* __restrict__ gcur, int NB) {
    for (int i = threadIdx.x; i < 8192; i += 256) {
        w1b[i] = f2b(W1[i]);
        w2b[i] = f2b(W2[i]);
    }
    for (int b = threadIdx.x; b < NB; b += 256) gcur[b] = b * CAP;
}

// ---------------------------------------------------------------------------
// Transpose inp [64][N] fp32 -> X [N][64] bf16 (staged in d_out; consumed by
// bagg_k before mlp_k overwrites d_out — stream-ordered, lifetimes disjoint).
// ---------------------------------------------------------------------------
__global__ void transpose_k(const float* __restrict__ inp,
                            ushort_t* __restrict__ X, int N) {
    __shared__ float tile[64][65];
    int tx = threadIdx.x & 63;
    int ty = threadIdx.x >> 6;
    int n0 = blockIdx.x * 64;
#pragma unroll
    for (int r = 0; r < 16; ++r) {
        int d = ty * 16 + r;
        int n = n0 + tx;
        if (n < N) tile[d][tx] = inp[(size_t)d * N + n];
    }
    __syncthreads();
#pragma unroll
    for (int r = 0; r < 16; ++r) {
        int nl = ty * 16 + r;
        int n  = n0 + nl;
        if (n < N) X[(size_t)n * 64 + tx] = f2b(tile[tx][nl]);
    }
}

// ---------------------------------------------------------------------------
// Two-sweep binning (block-private spans => same-block line ownership =>
// coalesced L2 write-back; avoids R4 scatter_k's 105 MB write-through):
//  sweep 1: count chunk edges per bucket (int LDS atomics),
//  claim:   one global atomicAdd per (block,bucket),
//  sweep 2: write pack=(dst_local<<24|src) into own span.
// ---------------------------------------------------------------------------
__global__ __launch_bounds__(512) void bin_k(
        const int* __restrict__ src, const int* __restrict__ dst,
        int* __restrict__ gcur, unsigned* __restrict__ bin, int E, int NB) {
    __shared__ int lcnt[NBMAX];
    __shared__ int gbase[NBMAX];
    __shared__ int lcur[NBMAX];
    int tid   = threadIdx.x;
    int chunk = (E + gridDim.x - 1) / gridDim.x;
    int s0 = blockIdx.x * chunk;
    int s1 = s0 + chunk;
    if (s1 > E) s1 = E;

    for (int b = tid; b < NB; b += 512) lcnt[b] = 0;
    __syncthreads();

    for (int e = s0 + tid; e < s1; e += 512)
        atomicAdd(&lcnt[dst[e] >> BSH], 1);
    __syncthreads();

    for (int b = tid; b < NB; b += 512) {
        int c = lcnt[b];
        gbase[b] = c ? atomicAdd(&gcur[b], c) : 0;
        lcur[b]  = 0;
    }
    __syncthreads();

    for (int e = s0 + tid; e < s1; e += 512) {
        int d = dst[e];
        int b = d >> BSH;
        int pos = gbase[b] + atomicAdd(&lcur[b], 1);
        if (pos < (b + 1) * CAP)   // overflow guard (statistically unreachable)
            bin[pos] = ((unsigned)(d & (BUCKW - 1)) << 24) | (unsigned)src[e];
    }
}

// ---------------------------------------------------------------------------
// Per-bucket aggregation v2: counting-sort the bucket's edges by local node
// in LDS (int atomics only), then ONE WAVE PER NODE walks its contiguous
// edge list with coalesced 128B X-row loads (lane=dim), 4-way unrolled,
// register accumulation, single dense agg-row store. No fp32 atomics, no
// divergent gathers. LDS ~14 KB.
// ---------------------------------------------------------------------------
__global__ __launch_bounds__(512) void bagg_k(
        const ushort_t* __restrict__ X, const unsigned* __restrict__ bin,
        const int* __restrict__ gcur, float* __restrict__ agg, int N) {
    __shared__ unsigned sl[CAP];      // 12 KB: bucket edges sorted by node
    __shared__ int ecnt[BUCKW];
    __shared__ int sc[BUCKW];         // scan -> exclusive offsets
    __shared__ int ecur[BUCKW];
    int tid  = threadIdx.x;
    int b    = blockIdx.x;
    int lo   = b << BSH;

    int cnt = gcur[b] - b * CAP;
    if (cnt > CAP) cnt = CAP;
    const unsigned* bb = bin + (size_t)b * CAP;

    if (tid < BUCKW) { ecnt[tid] = 0; }
    __syncthreads();

    for (int i = tid; i < cnt; i += 512)
        atomicAdd(&ecnt[bb[i] >> 24], 1);
    __syncthreads();

    if (tid < BUCKW) sc[tid] = ecnt[tid];
    __syncthreads();
#pragma unroll
    for (int off = 1; off < BUCKW; off <<= 1) {
        int v = 0;
        if (tid < BUCKW && tid >= off) v = sc[tid - off];
        __syncthreads();
        if (tid < BUCKW) sc[tid] += v;
        __syncthreads();
    }
    if (tid < BUCKW) { sc[tid] -= ecnt[tid]; ecur[tid] = 0; }   // exclusive
    __syncthreads();

    for (int i = tid; i < cnt; i += 512) {
        unsigned p = bb[i];
        int nl  = (int)(p >> 24);
        int pos = sc[nl] + atomicAdd(&ecur[nl], 1);
        sl[pos] = p;
    }
    __syncthreads();

    // one wave per node: coalesced row loads, register accumulation
    int wave = tid >> 6;               // 0..7
    int lane = tid & 63;
    for (int n = wave; n < BUCKW; n += 8) {
        int node = lo + n;
        if (node >= N) break;
        int s0 = sc[n];
        int c  = ecnt[n];
        float a0 = 0.f, a1 = 0.f, a2 = 0.f, a3 = 0.f;
        int i = 0;
        for (; i + 3 < c; i += 4) {
            unsigned p0 = sl[s0 + i],     p1 = sl[s0 + i + 1];
            unsigned p2 = sl[s0 + i + 2], p3 = sl[s0 + i + 3];
            a0 += bf2f(X[(size_t)(p0 & 0xFFFFFFu) * 64 + lane]);
            a1 += bf2f(X[(size_t)(p1 & 0xFFFFFFu) * 64 + lane]);
            a2 += bf2f(X[(size_t)(p2 & 0xFFFFFFu) * 64 + lane]);
            a3 += bf2f(X[(size_t)(p3 & 0xFFFFFFu) * 64 + lane]);
        }
        for (; i < c; ++i)
            a0 += bf2f(X[(size_t)(sl[s0 + i] & 0xFFFFFFu) * 64 + lane]);
        agg[(size_t)node * 64 + lane] = (a0 + a1) + (a2 + a3);
    }
}

// ---------------------------------------------------------------------------
// Fused 2-layer MLP via bf16 MFMA 16x16x32 (fp32 acc).
// Frag maps (verified, guide §3):
//   A[m=lane&15][k=(lane>>4)*8+j], B[k=(lane>>4)*8+j][n=lane&15],
//   D[m=(lane>>4)*4+r][n=lane&15]
// ---------------------------------------------------------------------------
#define HPITCH 136

__global__ __launch_bounds__(256) void mlp_k(
        const float* __restrict__ agg,
        const ushort_t* __restrict__ W1, const float* __restrict__ b1,
        const ushort_t* __restrict__ W2, const float* __restrict__ b2,
        float* __restrict__ out, int N) {
    __shared__ ushort_t h_s[4][16 * HPITCH];

    int wave = threadIdx.x >> 6;
    int lane = threadIdx.x & 63;
    int row  = lane & 15;
    int quad = lane >> 4;
    int n0   = blockIdx.x * 64 + wave * 16;

    int anode = n0 + row;
    if (anode > N - 1) anode = N - 1;
    const float* ap = agg + (size_t)anode * 64 + quad * 8;

    short8 a0, a1;
    {
        float4v f0 = *(const float4v*)(ap);
        float4v f1 = *(const float4v*)(ap + 4);
        float4v f2 = *(const float4v*)(ap + 32);
        float4v f3 = *(const float4v*)(ap + 36);
#pragma unroll
        for (int j = 0; j < 4; ++j) {
            a0[j]     = (short)f2b(f0[j]);
            a0[j + 4] = (short)f2b(f1[j]);
            a1[j]     = (short)f2b(f2[j]);
            a1[j + 4] = (short)f2b(f3[j]);
        }
    }

    float4v zero = {0.f, 0.f, 0.f, 0.f};
    float4v acc[8];
#pragma unroll
    for (int nt = 0; nt < 8; ++nt) acc[nt] = zero;

#pragma unroll
    for (int nt = 0; nt < 8; ++nt) {
        const ushort_t* wp = W1 + (size_t)(nt * 16 + row) * 64 + quad * 8;
        short8 bf0 = *(const short8*)(wp);
        short8 bf1 = *(const short8*)(wp + 32);
        acc[nt] = __builtin_amdgcn_mfma_f32_16x16x32_bf16(a0, bf0, acc[nt], 0, 0, 0);
        acc[nt] = __builtin_amdgcn_mfma_f32_16x16x32_bf16(a1, bf1, acc[nt], 0, 0, 0);
    }

    ushort_t* hw = h_s[wave];
#pragma unroll
    for (int nt = 0; nt < 8; ++nt) {
        float bias = b1[nt * 16 + row];
#pragma unroll
        for (int r = 0; r < 4; ++r) {
            float v = acc[nt][r] + bias;
            v = v > 0.f ? v : 0.f;
            hw[(quad * 4 + r) * HPITCH + nt * 16 + row] = f2b(v);
        }
    }
    __syncthreads();

    short8 a2[4];
#pragma unroll
    for (int kt = 0; kt < 4; ++kt)
        a2[kt] = *(const short8*)(hw + row * HPITCH + kt * 32 + quad * 8);

    float4v acc2[4];
#pragma unroll
    for (int nt = 0; nt < 4; ++nt) acc2[nt] = zero;

#pragma unroll
    for (int nt = 0; nt < 4; ++nt) {
#pragma unroll
        for (int kt = 0; kt < 4; ++kt) {
            short8 bfr = *(const short8*)(W2 + (size_t)(nt * 16 + row) * 128 +
                                          kt * 32 + quad * 8);
            acc2[nt] = __builtin_amdgcn_mfma_f32_16x16x32_bf16(a2[kt], bfr, acc2[nt], 0, 0, 0);
        }
    }

    int node = n0 + quad * 4;
    if (node < N) {
#pragma unroll
        for (int nt = 0; nt < 4; ++nt) {
            int ko = nt * 16 + row;
            float bias = b2[ko];
            float4v pk;
#pragma unroll
            for (int r = 0; r < 4; ++r) pk[r] = acc2[nt][r] + bias;
            *(float4v*)(out + (size_t)ko * N + node) = pk;
        }
    }
}

// ---------------------------------------------------------------------------
extern "C" void kernel_launch(void* const* d_in, const int* in_sizes, int n_in,
                              void* d_out, int out_size, void* d_ws, size_t ws_size,
                              hipStream_t stream) {
    const float* inp = (const float*)d_in[0];   // [64][N] fp32
    const int*   src = (const int*)d_in[1];
    const int*   dst = (const int*)d_in[2];
    const float* W1  = (const float*)d_in[3];   // [128][64] fp32
    const float* b1  = (const float*)d_in[4];   // [128] fp32
    const float* W2  = (const float*)d_in[5];   // [64][128] fp32
    const float* b2  = (const float*)d_in[6];   // [64] fp32
    float* out = (float*)d_out;                 // [64][N] fp32

    int N = in_sizes[0] / 64;
    int E = in_sizes[1];
    int NB = (N + BUCKW - 1) >> BSH;            // 782 for N=100000 (<= NBMAX)

    // ws: agg fp32[N*64] (25.6 MB) + w1b/w2b bf16 (32 KB) + gcur int[NBMAX]
    float*    agg  = (float*)d_ws;
    ushort_t* w1b  = (ushort_t*)((char*)d_ws + (size_t)N * 64 * sizeof(float));
    ushort_t* w2b  = w1b + 8192;
    int*      gcur = (int*)(w2b + 8192);

    // d_out staging (dead before mlp_k overwrites d_out):
    //   X bf16[N*64] (12.8 MB) | bin u32[NB*CAP] (9.6 MB)  — total 22.4 MB
    char*     ob  = (char*)d_out;
    ushort_t* X   = (ushort_t*)ob;
    unsigned* bin = (unsigned*)(ob + (size_t)N * 64 * 2);

    convw_k<<<1, 256, 0, stream>>>(W1, W2, w1b, w2b, gcur, NB);

    int tb = (N + 63) / 64;
    transpose_k<<<tb, 256, 0, stream>>>(inp, X, N);

    bin_k<<<128, 512, 0, stream>>>(src, dst, gcur, bin, E, NB);
    bagg_k<<<NB, 512, 0, stream>>>(X, bin, gcur, agg, N);

    mlp_k<<<tb, 256, 0, stream>>>(agg, w1b, b1, w2b, b2, out, N);
}

// Round 9
// 212.525 us; speedup vs baseline: 4.2247x; 1.0060x over previous
//
#include <hip/hip_runtime.h>
#include <hip/hip_bf16.h>
#include <stdint.h>

typedef unsigned short ushort_t;
using short8   = __attribute__((ext_vector_type(8))) short;
using float4v  = __attribute__((ext_vector_type(4))) float;

#define BSH    6          // bucket = 64 consecutive dst nodes
#define BUCKW  64
#define CAP    1536       // per-bucket capacity (avg 1024, +16 sigma)
#define NBMAX  2048

__device__ __forceinline__ float bf2f(ushort_t u) {
    union { unsigned int i; float f; } v;
    v.i = ((unsigned int)u) << 16;
    return v.f;
}
__device__ __forceinline__ ushort_t f2b(float f) {
    union { float f; unsigned int i; } v;
    v.f = f;
    unsigned int u = v.i;
    unsigned int r = (u + 0x7fffu + ((u >> 16) & 1u)) >> 16;   // RNE
    return (ushort_t)r;
}

// ---------------------------------------------------------------------------
// Transpose inp [64][N] fp32 -> X [N][64] bf16 (staged in d_out; consumed by
// bagg_k before mlp_k overwrites d_out). Block 0 additionally converts the
// weights to bf16 and inits the per-bucket cursors (saves a dispatch).
// ---------------------------------------------------------------------------
__global__ void transpose_k(const float* __restrict__ inp,
                            ushort_t* __restrict__ X, int N,
                            const float* __restrict__ W1,
                            const float* __restrict__ W2,
                            ushort_t* __restrict__ w1b,
                            ushort_t* __restrict__ w2b,
                            int* __restrict__ gcur, int NB) {
    if (blockIdx.x == 0) {
        for (int i = threadIdx.x; i < 8192; i += 256) {
            w1b[i] = f2b(W1[i]);
            w2b[i] = f2b(W2[i]);
        }
        for (int b = threadIdx.x; b < NB; b += 256) gcur[b] = b * CAP;
    }
    __shared__ float tile[64][65];
    int tx = threadIdx.x & 63;
    int ty = threadIdx.x >> 6;
    int n0 = blockIdx.x * 64;
#pragma unroll
    for (int r = 0; r < 16; ++r) {
        int d = ty * 16 + r;
        int n = n0 + tx;
        if (n < N) tile[d][tx] = inp[(size_t)d * N + n];
    }
    __syncthreads();
#pragma unroll
    for (int r = 0; r < 16; ++r) {
        int nl = ty * 16 + r;
        int n  = n0 + nl;
        if (n < N) X[(size_t)n * 64 + tx] = f2b(tile[tx][nl]);
    }
}

// ---------------------------------------------------------------------------
// Two-sweep binning (block-private spans => same-block line ownership =>
// coalesced L2 write-back). 128 blocks x 1024 threads: span avg = 8 edges
// = 32B (same line behavior as R8's 128x512, 2x wave parallelism).
// ---------------------------------------------------------------------------
__global__ __launch_bounds__(1024) void bin_k(
        const int* __restrict__ src, const int* __restrict__ dst,
        int* __restrict__ gcur, unsigned* __restrict__ bin, int E, int NB) {
    __shared__ int lcnt[NBMAX];
    __shared__ int gbase[NBMAX];
    __shared__ int lcur[NBMAX];
    int tid   = threadIdx.x;
    int chunk = (E + gridDim.x - 1) / gridDim.x;
    int s0 = blockIdx.x * chunk;
    int s1 = s0 + chunk;
    if (s1 > E) s1 = E;

    for (int b = tid; b < NB; b += 1024) lcnt[b] = 0;
    __syncthreads();

    for (int e = s0 + tid; e < s1; e += 1024)
        atomicAdd(&lcnt[dst[e] >> BSH], 1);
    __syncthreads();

    for (int b = tid; b < NB; b += 1024) {
        int c = lcnt[b];
        gbase[b] = c ? atomicAdd(&gcur[b], c) : 0;
        lcur[b]  = 0;
    }
    __syncthreads();

    for (int e = s0 + tid; e < s1; e += 1024) {
        int d = dst[e];
        int b = d >> BSH;
        int pos = gbase[b] + atomicAdd(&lcur[b], 1);
        if (pos < (b + 1) * CAP)   // overflow guard (statistically unreachable)
            bin[pos] = ((unsigned)(d & (BUCKW - 1)) << 24) | (unsigned)src[e];
    }
}

// ---------------------------------------------------------------------------
// Per-bucket aggregation: counting-sort bucket edges by local node in LDS
// (int atomics only), then ONE WAVE PER NODE walks its contiguous edge list
// with coalesced 128B X-row loads (lane=dim), 8-way unrolled, register
// accumulation, single dense agg-row store. 256 thr / ~7 KB LDS => high
// occupancy (6+ blocks/CU target vs R8's 44%).
// ---------------------------------------------------------------------------
__global__ __launch_bounds__(256) void bagg_k(
        const ushort_t* __restrict__ X, const unsigned* __restrict__ bin,
        const int* __restrict__ gcur, float* __restrict__ agg, int N) {
    __shared__ unsigned sl[CAP];      // 6 KB
    __shared__ int ecnt[BUCKW];
    __shared__ int sc[BUCKW];
    __shared__ int ecur[BUCKW];
    int tid = threadIdx.x;
    int b   = blockIdx.x;
    int lo  = b << BSH;

    int cnt = gcur[b] - b * CAP;
    if (cnt > CAP) cnt = CAP;
    const unsigned* bb = bin + (size_t)b * CAP;

    if (tid < BUCKW) ecnt[tid] = 0;
    __syncthreads();

    for (int i = tid; i < cnt; i += 256)
        atomicAdd(&ecnt[bb[i] >> 24], 1);
    __syncthreads();

    if (tid < BUCKW) sc[tid] = ecnt[tid];
    __syncthreads();
#pragma unroll
    for (int off = 1; off < BUCKW; off <<= 1) {
        int v = 0;
        if (tid < BUCKW && tid >= off) v = sc[tid - off];
        __syncthreads();
        if (tid < BUCKW) sc[tid] += v;
        __syncthreads();
    }
    if (tid < BUCKW) { sc[tid] -= ecnt[tid]; ecur[tid] = 0; }   // exclusive
    __syncthreads();

    for (int i = tid; i < cnt; i += 256) {
        unsigned p = bb[i];
        int nl  = (int)(p >> 24);
        int pos = sc[nl] + atomicAdd(&ecur[nl], 1);
        sl[pos] = p;
    }
    __syncthreads();

    int wave = tid >> 6;               // 0..3
    int lane = tid & 63;
    for (int n = wave; n < BUCKW; n += 4) {
        int node = lo + n;
        if (node >= N) break;
        int s0 = sc[n];
        int c  = ecnt[n];
        float a0 = 0.f, a1 = 0.f, a2 = 0.f, a3 = 0.f;
        int i = 0;
        for (; i + 7 < c; i += 8) {
            unsigned p0 = sl[s0 + i],     p1 = sl[s0 + i + 1];
            unsigned p2 = sl[s0 + i + 2], p3 = sl[s0 + i + 3];
            unsigned p4 = sl[s0 + i + 4], p5 = sl[s0 + i + 5];
            unsigned p6 = sl[s0 + i + 6], p7 = sl[s0 + i + 7];
            a0 += bf2f(X[(size_t)(p0 & 0xFFFFFFu) * 64 + lane]);
            a1 += bf2f(X[(size_t)(p1 & 0xFFFFFFu) * 64 + lane]);
            a2 += bf2f(X[(size_t)(p2 & 0xFFFFFFu) * 64 + lane]);
            a3 += bf2f(X[(size_t)(p3 & 0xFFFFFFu) * 64 + lane]);
            a0 += bf2f(X[(size_t)(p4 & 0xFFFFFFu) * 64 + lane]);
            a1 += bf2f(X[(size_t)(p5 & 0xFFFFFFu) * 64 + lane]);
            a2 += bf2f(X[(size_t)(p6 & 0xFFFFFFu) * 64 + lane]);
            a3 += bf2f(X[(size_t)(p7 & 0xFFFFFFu) * 64 + lane]);
        }
        for (; i < c; ++i)
            a0 += bf2f(X[(size_t)(sl[s0 + i] & 0xFFFFFFu) * 64 + lane]);
        agg[(size_t)node * 64 + lane] = (a0 + a1) + (a2 + a3);
    }
}

// ---------------------------------------------------------------------------
// Fused 2-layer MLP via bf16 MFMA 16x16x32 (fp32 acc).
// Frag maps (verified, guide §3):
//   A[m=lane&15][k=(lane>>4)*8+j], B[k=(lane>>4)*8+j][n=lane&15],
//   D[m=(lane>>4)*4+r][n=lane&15]
// ---------------------------------------------------------------------------
#define HPITCH 136

__global__ __launch_bounds__(256) void mlp_k(
        const float* __restrict__ agg,
        const ushort_t* __restrict__ W1, const float* __restrict__ b1,
        const ushort_t* __restrict__ W2, const float* __restrict__ b2,
        float* __restrict__ out, int N) {
    __shared__ ushort_t h_s[4][16 * HPITCH];

    int wave = threadIdx.x >> 6;
    int lane = threadIdx.x & 63;
    int row  = lane & 15;
    int quad = lane >> 4;
    int n0   = blockIdx.x * 64 + wave * 16;

    int anode = n0 + row;
    if (anode > N - 1) anode = N - 1;
    const float* ap = agg + (size_t)anode * 64 + quad * 8;

    short8 a0, a1;
    {
        float4v f0 = *(const float4v*)(ap);
        float4v f1 = *(const float4v*)(ap + 4);
        float4v f2 = *(const float4v*)(ap + 32);
        float4v f3 = *(const float4v*)(ap + 36);
#pragma unroll
        for (int j = 0; j < 4; ++j) {
            a0[j]     = (short)f2b(f0[j]);
            a0[j + 4] = (short)f2b(f1[j]);
            a1[j]     = (short)f2b(f2[j]);
            a1[j + 4] = (short)f2b(f3[j]);
        }
    }

    float4v zero = {0.f, 0.f, 0.f, 0.f};
    float4v acc[8];
#pragma unroll
    for (int nt = 0; nt < 8; ++nt) acc[nt] = zero;

#pragma unroll
    for (int nt = 0; nt < 8; ++nt) {
        const ushort_t* wp = W1 + (size_t)(nt * 16 + row) * 64 + quad * 8;
        short8 bf0 = *(const short8*)(wp);
        short8 bf1 = *(const short8*)(wp + 32);
        acc[nt] = __builtin_amdgcn_mfma_f32_16x16x32_bf16(a0, bf0, acc[nt], 0, 0, 0);
        acc[nt] = __builtin_amdgcn_mfma_f32_16x16x32_bf16(a1, bf1, acc[nt], 0, 0, 0);
    }

    ushort_t* hw = h_s[wave];
#pragma unroll
    for (int nt = 0; nt < 8; ++nt) {
        float bias = b1[nt * 16 + row];
#pragma unroll
        for (int r = 0; r < 4; ++r) {
            float v = acc[nt][r] + bias;
            v = v > 0.f ? v : 0.f;
            hw[(quad * 4 + r) * HPITCH + nt * 16 + row] = f2b(v);
        }
    }
    __syncthreads();

    short8 a2[4];
#pragma unroll
    for (int kt = 0; kt < 4; ++kt)
        a2[kt] = *(const short8*)(hw + row * HPITCH + kt * 32 + quad * 8);

    float4v acc2[4];
#pragma unroll
    for (int nt = 0; nt < 4; ++nt) acc2[nt] = zero;

#pragma unroll
    for (int nt = 0; nt < 4; ++nt) {
#pragma unroll
        for (int kt = 0; kt < 4; ++kt) {
            short8 bfr = *(const short8*)(W2 + (size_t)(nt * 16 + row) * 128 +
                                          kt * 32 + quad * 8);
            acc2[nt] = __builtin_amdgcn_mfma_f32_16x16x32_bf16(a2[kt], bfr, acc2[nt], 0, 0, 0);
        }
    }

    int node = n0 + quad * 4;
    if (node < N) {
#pragma unroll
        for (int nt = 0; nt < 4; ++nt) {
            int ko = nt * 16 + row;
            float bias = b2[ko];
            float4v pk;
#pragma unroll
            for (int r = 0; r < 4; ++r) pk[r] = acc2[nt][r] + bias;
            *(float4v*)(out + (size_t)ko * N + node) = pk;
        }
    }
}

// ---------------------------------------------------------------------------
extern "C" void kernel_launch(void* const* d_in, const int* in_sizes, int n_in,
                              void* d_out, int out_size, void* d_ws, size_t ws_size,
                              hipStream_t stream) {
    const float* inp = (const float*)d_in[0];   // [64][N] fp32
    const int*   src = (const int*)d_in[1];
    const int*   dst = (const int*)d_in[2];
    const float* W1  = (const float*)d_in[3];   // [128][64] fp32
    const float* b1  = (const float*)d_in[4];   // [128] fp32
    const float* W2  = (const float*)d_in[5];   // [64][128] fp32
    const float* b2  = (const float*)d_in[6];   // [64] fp32
    float* out = (float*)d_out;                 // [64][N] fp32

    int N = in_sizes[0] / 64;
    int E = in_sizes[1];
    int NB = (N + BUCKW - 1) >> BSH;            // 1563 for N=100000 (<= NBMAX)

    // ws: agg fp32[N*64] (25.6 MB) + w1b/w2b bf16 (32 KB) + gcur int[NBMAX]
    float*    agg  = (float*)d_ws;
    ushort_t* w1b  = (ushort_t*)((char*)d_ws + (size_t)N * 64 * sizeof(float));
    ushort_t* w2b  = w1b + 8192;
    int*      gcur = (int*)(w2b + 8192);

    // d_out staging (dead before mlp_k overwrites d_out):
    //   X bf16[N*64] (12.8 MB) | bin u32[NB*CAP] (9.6 MB)  — total 22.4 MB
    char*     ob  = (char*)d_out;
    ushort_t* X   = (ushort_t*)ob;
    unsigned* bin = (unsigned*)(ob + (size_t)N * 64 * 2);

    int tb = (N + 63) / 64;
    transpose_k<<<tb, 256, 0, stream>>>(inp, X, N, W1, W2, w1b, w2b, gcur, NB);

    bin_k<<<128, 1024, 0, stream>>>(src, dst, gcur, bin, E, NB);
    bagg_k<<<NB, 256, 0, stream>>>(X, bin, gcur, agg, N);

    mlp_k<<<tb, 256, 0, stream>>>(agg, w1b, b1, w2b, b2, out, N);
}

// Round 10
// 204.079 us; speedup vs baseline: 4.3996x; 1.0414x over previous
//
#include <hip/hip_runtime.h>
#include <hip/hip_bf16.h>
#include <stdint.h>

typedef unsigned short ushort_t;
using short8   = __attribute__((ext_vector_type(8))) short;
using float4v  = __attribute__((ext_vector_type(4))) float;

#define BSH    6          // bucket = 64 consecutive dst nodes
#define BUCKW  64
#define CAP    1536       // per-bucket capacity (avg 1024, +16 sigma)
#define NBMAX  2048
#define TPITCH 266        // transpose tile pitch (ushorts): 133 dwords, odd -> no conflicts
#define BINB   128        // binning blocks

__device__ __forceinline__ float bf2f(ushort_t u) {
    union { unsigned int i; float f; } v;
    v.i = ((unsigned int)u) << 16;
    return v.f;
}
__device__ __forceinline__ ushort_t f2b(float f) {
    union { float f; unsigned int i; } v;
    v.f = f;
    unsigned int u = v.i;
    unsigned int r = (u + 0x7fffu + ((u >> 16) & 1u)) >> 16;   // RNE
    return (ushort_t)r;
}
__device__ __forceinline__ float blo2f(unsigned v) {   // low bf16 of dword
    union { unsigned i; float f; } u; u.i = v << 16; return u.f;
}
__device__ __forceinline__ float bhi2f(unsigned v) {   // high bf16 of dword
    union { unsigned i; float f; } u; u.i = v & 0xFFFF0000u; return u.f;
}

// ---------------------------------------------------------------------------
// prep_k: heterogeneous roles, 1024 threads.
//  blocks [0, TB):   transpose 256 nodes each: inp [64][N] fp32 -> X [N][64]
//                    bf16 (block 0 also converts weights to bf16).
//  blocks [TB, +BINB): two-sweep binning (block-private spans => same-block
//                    line ownership => coalesced write-back). gcur is
//                    pre-zeroed by hipMemsetAsync; bases are bucket-relative.
// ---------------------------------------------------------------------------
__global__ __launch_bounds__(1024) void prep_k(
        const float* __restrict__ inp, ushort_t* __restrict__ X, int N,
        const float* __restrict__ W1, const float* __restrict__ W2,
        ushort_t* __restrict__ w1b, ushort_t* __restrict__ w2b,
        const int* __restrict__ src, const int* __restrict__ dst,
        int* __restrict__ gcur, unsigned* __restrict__ bin, int E,
        int NB, int TB) {
    __shared__ __align__(16) char smem[64 * TPITCH * 2];   // 34048 B
    int tid = threadIdx.x;

    if ((int)blockIdx.x < TB) {
        // ---------------- transpose role ----------------
        if (blockIdx.x == 0) {
            for (int i = tid; i < 8192; i += 1024) {
                w1b[i] = f2b(W1[i]);
                w2b[i] = f2b(W2[i]);
            }
        }
        ushort_t* tile = (ushort_t*)smem;       // [64][TPITCH]
        int w    = tid >> 6;                    // 0..15
        int lane = tid & 63;
        int n0   = blockIdx.x * 256;
        int col  = (w >> 2) * 64 + lane;        // 0..255
        int nc   = n0 + col;
#pragma unroll
        for (int r = 0; r < 16; ++r) {
            int d = (w & 3) * 16 + r;
            if (nc < N) tile[d * TPITCH + col] = f2b(inp[(size_t)d * N + nc]);
        }
        __syncthreads();
#pragma unroll
        for (int r = 0; r < 16; ++r) {
            int nl = w * 16 + r;
            int n  = n0 + nl;
            if (n < N) X[(size_t)n * 64 + lane] = tile[lane * TPITCH + nl];
        }
    } else {
        // ---------------- binning role ----------------
        int* lcnt  = (int*)smem;
        int* gbase = lcnt + NBMAX;
        int* lcur  = gbase + NBMAX;
        int bid   = blockIdx.x - TB;
        int chunk = (E + BINB - 1) / BINB;
        int s0 = bid * chunk;
        int s1 = s0 + chunk;
        if (s1 > E) s1 = E;

        for (int b = tid; b < NB; b += 1024) lcnt[b] = 0;
        __syncthreads();

        for (int e = s0 + tid; e < s1; e += 1024)
            atomicAdd(&lcnt[dst[e] >> BSH], 1);
        __syncthreads();

        for (int b = tid; b < NB; b += 1024) {
            int c = lcnt[b];
            gbase[b] = c ? atomicAdd(&gcur[b], c) : 0;   // relative base
            lcur[b]  = 0;
        }
        __syncthreads();

        for (int e = s0 + tid; e < s1; e += 1024) {
            int d = dst[e];
            int b = d >> BSH;
            int pos = gbase[b] + atomicAdd(&lcur[b], 1);
            if (pos < CAP)   // overflow guard (statistically unreachable)
                bin[(size_t)b * CAP + pos] =
                    ((unsigned)(d & (BUCKW - 1)) << 24) | (unsigned)src[e];
        }
    }
}

// ---------------------------------------------------------------------------
// Per-bucket aggregation: counting-sort bucket edges by local node in LDS,
// then one wave per node. Gather uses DWORD-PAIR mapping: lanes 0-31 read
// row of edge e (32x4B), lanes 32-63 row of edge e+1 => 2 edges per load
// instr, 16 edges in flight at unroll 8 (2x R9 concurrency). Cross-half
// combine via shfl(+32); agg stored bf16 (halves write traffic).
// ---------------------------------------------------------------------------
__global__ __launch_bounds__(256) void bagg_k(
        const unsigned* __restrict__ Xu, const unsigned* __restrict__ bin,
        const int* __restrict__ gcur, unsigned* __restrict__ aggu, int N) {
    __shared__ unsigned sl[CAP];      // 6 KB
    __shared__ int ecnt[BUCKW];
    __shared__ int sc[BUCKW];
    __shared__ int ecur[BUCKW];
    int tid = threadIdx.x;
    int b   = blockIdx.x;
    int lo  = b << BSH;

    int cnt = gcur[b];
    if (cnt > CAP) cnt = CAP;
    const unsigned* bb = bin + (size_t)b * CAP;

    if (tid < BUCKW) ecnt[tid] = 0;
    __syncthreads();

    for (int i = tid; i < cnt; i += 256)
        atomicAdd(&ecnt[bb[i] >> 24], 1);
    __syncthreads();

    if (tid < BUCKW) sc[tid] = ecnt[tid];
    __syncthreads();
#pragma unroll
    for (int off = 1; off < BUCKW; off <<= 1) {
        int v = 0;
        if (tid < BUCKW && tid >= off) v = sc[tid - off];
        __syncthreads();
        if (tid < BUCKW) sc[tid] += v;
        __syncthreads();
    }
    if (tid < BUCKW) { sc[tid] -= ecnt[tid]; ecur[tid] = 0; }   // exclusive
    __syncthreads();

    for (int i = tid; i < cnt; i += 256) {
        unsigned p = bb[i];
        int nl  = (int)(p >> 24);
        int pos = sc[nl] + atomicAdd(&ecur[nl], 1);
        sl[pos] = p;
    }
    __syncthreads();

    int wave = tid >> 6;               // 0..3
    int lane = tid & 63;
    int half = lane >> 5;              // 0: even edges, 1: odd edges
    int c2   = lane & 31;              // dword index within row (2 dims)

    for (int n = wave; n < BUCKW; n += 4) {
        int node = lo + n;
        if (node >= N) break;
        int s0 = sc[n];
        int c  = ecnt[n];
        float alo0 = 0.f, ahi0 = 0.f, alo1 = 0.f, ahi1 = 0.f;
        int i = 0;
        for (; i + 16 <= c; i += 16) {
            unsigned p0 = sl[s0 + i +  0 + half], p1 = sl[s0 + i +  2 + half];
            unsigned p2 = sl[s0 + i +  4 + half], p3 = sl[s0 + i +  6 + half];
            unsigned p4 = sl[s0 + i +  8 + half], p5 = sl[s0 + i + 10 + half];
            unsigned p6 = sl[s0 + i + 12 + half], p7 = sl[s0 + i + 14 + half];
            unsigned v0 = Xu[(size_t)(p0 & 0xFFFFFFu) * 32 + c2];
            unsigned v1 = Xu[(size_t)(p1 & 0xFFFFFFu) * 32 + c2];
            unsigned v2 = Xu[(size_t)(p2 & 0xFFFFFFu) * 32 + c2];
            unsigned v3 = Xu[(size_t)(p3 & 0xFFFFFFu) * 32 + c2];
            unsigned v4 = Xu[(size_t)(p4 & 0xFFFFFFu) * 32 + c2];
            unsigned v5 = Xu[(size_t)(p5 & 0xFFFFFFu) * 32 + c2];
            unsigned v6 = Xu[(size_t)(p6 & 0xFFFFFFu) * 32 + c2];
            unsigned v7 = Xu[(size_t)(p7 & 0xFFFFFFu) * 32 + c2];
            alo0 += blo2f(v0); ahi0 += bhi2f(v0);
            alo1 += blo2f(v1); ahi1 += bhi2f(v1);
            alo0 += blo2f(v2); ahi0 += bhi2f(v2);
            alo1 += blo2f(v3); ahi1 += bhi2f(v3);
            alo0 += blo2f(v4); ahi0 += bhi2f(v4);
            alo1 += blo2f(v5); ahi1 += bhi2f(v5);
            alo0 += blo2f(v6); ahi0 += bhi2f(v6);
            alo1 += blo2f(v7); ahi1 += bhi2f(v7);
        }
        for (; i + 2 <= c; i += 2) {
            unsigned p = sl[s0 + i + half];
            unsigned v = Xu[(size_t)(p & 0xFFFFFFu) * 32 + c2];
            alo0 += blo2f(v); ahi0 += bhi2f(v);
        }
        if (i + half < c) {            // odd tail: half 0 only
            unsigned p = sl[s0 + i + half];
            unsigned v = Xu[(size_t)(p & 0xFFFFFFu) * 32 + c2];
            alo1 += blo2f(v); ahi1 += bhi2f(v);
        }
        float alo = alo0 + alo1;
        float ahi = ahi0 + ahi1;
        float blo = __shfl(alo, lane + 32);
        float bhi = __shfl(ahi, lane + 32);
        if (half == 0) {
            alo += blo; ahi += bhi;
            aggu[(size_t)node * 32 + c2] =
                (unsigned)f2b(alo) | ((unsigned)f2b(ahi) << 16);
        }
    }
}

// ---------------------------------------------------------------------------
// Fused 2-layer MLP via bf16 MFMA 16x16x32 (fp32 acc). agg is bf16 [N][64]
// => A-fragments load directly as short8 (no cvt, half the fetch).
// Frag maps (verified, guide §3):
//   A[m=lane&15][k=(lane>>4)*8+j], B[k=(lane>>4)*8+j][n=lane&15],
//   D[m=(lane>>4)*4+r][n=lane&15]
// ---------------------------------------------------------------------------
#define HPITCH 136

__global__ __launch_bounds__(256) void mlp_k(
        const ushort_t* __restrict__ aggb,
        const ushort_t* __restrict__ W1, const float* __restrict__ b1,
        const ushort_t* __restrict__ W2, const float* __restrict__ b2,
        float* __restrict__ out, int N) {
    __shared__ ushort_t h_s[4][16 * HPITCH];

    int wave = threadIdx.x >> 6;
    int lane = threadIdx.x & 63;
    int row  = lane & 15;
    int quad = lane >> 4;
    int n0   = blockIdx.x * 64 + wave * 16;

    int anode = n0 + row;
    if (anode > N - 1) anode = N - 1;
    const ushort_t* ap = aggb + (size_t)anode * 64;
    short8 a0 = *(const short8*)(ap + quad * 8);
    short8 a1 = *(const short8*)(ap + 32 + quad * 8);

    float4v zero = {0.f, 0.f, 0.f, 0.f};
    float4v acc[8];
#pragma unroll
    for (int nt = 0; nt < 8; ++nt) acc[nt] = zero;

#pragma unroll
    for (int nt = 0; nt < 8; ++nt) {
        const ushort_t* wp = W1 + (size_t)(nt * 16 + row) * 64 + quad * 8;
        short8 bf0 = *(const short8*)(wp);
        short8 bf1 = *(const short8*)(wp + 32);
        acc[nt] = __builtin_amdgcn_mfma_f32_16x16x32_bf16(a0, bf0, acc[nt], 0, 0, 0);
        acc[nt] = __builtin_amdgcn_mfma_f32_16x16x32_bf16(a1, bf1, acc[nt], 0, 0, 0);
    }

    ushort_t* hw = h_s[wave];
#pragma unroll
    for (int nt = 0; nt < 8; ++nt) {
        float bias = b1[nt * 16 + row];
#pragma unroll
        for (int r = 0; r < 4; ++r) {
            float v = acc[nt][r] + bias;
            v = v > 0.f ? v : 0.f;
            hw[(quad * 4 + r) * HPITCH + nt * 16 + row] = f2b(v);
        }
    }
    __syncthreads();

    short8 a2[4];
#pragma unroll
    for (int kt = 0; kt < 4; ++kt)
        a2[kt] = *(const short8*)(hw + row * HPITCH + kt * 32 + quad * 8);

    float4v acc2[4];
#pragma unroll
    for (int nt = 0; nt < 4; ++nt) acc2[nt] = zero;

#pragma unroll
    for (int nt = 0; nt < 4; ++nt) {
#pragma unroll
        for (int kt = 0; kt < 4; ++kt) {
            short8 bfr = *(const short8*)(W2 + (size_t)(nt * 16 + row) * 128 +
                                          kt * 32 + quad * 8);
            acc2[nt] = __builtin_amdgcn_mfma_f32_16x16x32_bf16(a2[kt], bfr, acc2[nt], 0, 0, 0);
        }
    }

    int node = n0 + quad * 4;
    if (node < N) {
#pragma unroll
        for (int nt = 0; nt < 4; ++nt) {
            int ko = nt * 16 + row;
            float bias = b2[ko];
            float4v pk;
#pragma unroll
            for (int r = 0; r < 4; ++r) pk[r] = acc2[nt][r] + bias;
            *(float4v*)(out + (size_t)ko * N + node) = pk;
        }
    }
}

// ---------------------------------------------------------------------------
extern "C" void kernel_launch(void* const* d_in, const int* in_sizes, int n_in,
                              void* d_out, int out_size, void* d_ws, size_t ws_size,
                              hipStream_t stream) {
    const float* inp = (const float*)d_in[0];   // [64][N] fp32
    const int*   src = (const int*)d_in[1];
    const int*   dst = (const int*)d_in[2];
    const float* W1  = (const float*)d_in[3];   // [128][64] fp32
    const float* b1  = (const float*)d_in[4];   // [128] fp32
    const float* W2  = (const float*)d_in[5];   // [64][128] fp32
    const float* b2  = (const float*)d_in[6];   // [64] fp32
    float* out = (float*)d_out;                 // [64][N] fp32

    int N  = in_sizes[0] / 64;
    int E  = in_sizes[1];
    int NB = (N + BUCKW - 1) >> BSH;            // 1563 for N=100000 (<= NBMAX)

    // ws: aggb bf16[N*64] (12.8 MB) + w1b/w2b bf16 (32 KB) + gcur int[NBMAX]
    ushort_t* aggb = (ushort_t*)d_ws;
    ushort_t* w1b  = aggb + (size_t)N * 64;
    ushort_t* w2b  = w1b + 8192;
    int*      gcur = (int*)(w2b + 8192);

    // d_out staging (dead before mlp_k overwrites d_out):
    //   X bf16[N*64] (12.8 MB) | bin u32[NB*CAP] (9.6 MB)  — total 22.4 MB
    char*     ob  = (char*)d_out;
    ushort_t* X   = (ushort_t*)ob;
    unsigned* bin = (unsigned*)(ob + (size_t)N * 64 * 2);

    hipMemsetAsync(gcur, 0, NB * sizeof(int), stream);   // relative cursors

    int TB = (N + 255) / 256;
    prep_k<<<TB + BINB, 1024, 0, stream>>>(inp, X, N, W1, W2, w1b, w2b,
                                           src, dst, gcur, bin, E, NB, TB);

    bagg_k<<<NB, 256, 0, stream>>>((const unsigned*)X, bin, gcur,
                                   (unsigned*)aggb, N);

    int tb = (N + 63) / 64;
    mlp_k<<<tb, 256, 0, stream>>>(aggb, w1b, b1, w2b, b2, out, N);
}